// Round 1
// baseline (316.927 us; speedup 1.0000x reference)
//
#include <hip/hip_runtime.h>

#define HW 262144          // 512*512 pixels per image
#define NBINS 1024         // 10-bit histogram (8 exp | 2 mantissa), value>=0
#define RSLOT 2            // lane-parity replication factor
#define NSLOT (NBINS * RSLOT)
#define BPI 16             // blocks per image in kernel 1 (slice = 16384 px)
#define T1 512             // threads per block, kernel 1 (8 waves)
#define POS_THRESH 0.1f
#define FALLBACK_POS 1000.0f
#define FIX_SCALE 16777216.0f     // 2^24 fixed-point scale for loss sums
#define INV_FIX   (1.0 / 16777216.0)
#define CNT_SHIFT 44
#define SUM_MASK  ((1ULL << CNT_SHIFT) - 1)

// ---------------------------------------------------------------------------
// Kernel 1: one streaming pass. Per block: 16384-px slice of one image.
// Packed LDS histogram (count<<44 | fixed-point sum) of negative losses for
// region+affinity -> ONE ds_add_u64 per negative pixel-op.
//   * R=2 lane-parity slot replication: slot = bin*2 + (lane&1). Halves
//     within-wave same-address atomic serialization; even/odd lanes land on
//     adjacent distinct bank-pairs. Integer packed adds -> bit-exact remerge.
//   * T1=512, BPI=16: grid = 1024 blocks = exactly 4 blocks/CU x 8 waves
//     = 32 waves/CU (100% occupancy), single generation, no tail.
// 32 KB LDS histogram. 2x unrolled loads: 10 float4 in flight per iteration.
// ---------------------------------------------------------------------------
__global__ __launch_bounds__(T1, 8) void maploss_hist(
    const float* __restrict__ rlab, const float* __restrict__ alab,
    const float* __restrict__ rpre, const float* __restrict__ apre,
    const float* __restrict__ mask,
    unsigned long long* __restrict__ g_hist,  // [2*B][NBINS] packed
    float* __restrict__ g_pos)                // [2*B]
{
    __shared__ unsigned long long s_hist[2][NSLOT];   // 32 KB
    __shared__ float s_red[2][T1 / 64];

    const int tid   = threadIdx.x;
    const int slice = blockIdx.x;   // 0..BPI-1
    const int img   = blockIdx.y;   // 0..B-1
    const int par   = tid & 1;      // lane-parity replication slot

    for (int i = tid; i < NSLOT; i += T1) {
        s_hist[0][i] = 0ull;
        s_hist[1][i] = 0ull;
    }
    __syncthreads();

    const size_t base = (size_t)img * HW + (size_t)slice * (HW / BPI);
    const float4* rl4 = (const float4*)(rlab + base);
    const float4* al4 = (const float4*)(alab + base);
    const float4* rp4 = (const float4*)(rpre + base);
    const float4* ap4 = (const float4*)(apre + base);
    const float4* m4  = (const float4*)(mask + base);

    float posr = 0.f, posa = 0.f;

    auto proc = [&](float lab, float pre, float mm, int op, float& pacc) {
        float d = pre - lab;
        float l = d * d * mm;
        if (lab > POS_THRESH) {
            pacc += l;
        } else {
            unsigned int b = __float_as_uint(l) >> 21;   // monotone for l>=0
            if (b >= NBINS) b = NBINS - 1;               // safety clamp
            unsigned long long pk = (1ULL << CNT_SHIFT) |
                (unsigned long long)(fminf(l, 2.0f) * FIX_SCALE);
            atomicAdd(&s_hist[op][(b << 1) | par], pk);
        }
    };

    const int NV = (HW / BPI) / 4;            // 4096 float4 per slice
    for (int i0 = tid; i0 < NV; i0 += 2 * T1) {
        const int i1 = i0 + T1;               // NV = 8*T1 -> always in range
        float4 rl0 = rl4[i0], rl1 = rl4[i1];
        float4 al0 = al4[i0], al1 = al4[i1];
        float4 rp0 = rp4[i0], rp1 = rp4[i1];
        float4 ap0 = ap4[i0], ap1 = ap4[i1];
        float4 m0  = m4[i0],  m1  = m4[i1];

        proc(rl0.x, rp0.x, m0.x, 0, posr);  proc(al0.x, ap0.x, m0.x, 1, posa);
        proc(rl0.y, rp0.y, m0.y, 0, posr);  proc(al0.y, ap0.y, m0.y, 1, posa);
        proc(rl0.z, rp0.z, m0.z, 0, posr);  proc(al0.z, ap0.z, m0.z, 1, posa);
        proc(rl0.w, rp0.w, m0.w, 0, posr);  proc(al0.w, ap0.w, m0.w, 1, posa);

        proc(rl1.x, rp1.x, m1.x, 0, posr);  proc(al1.x, ap1.x, m1.x, 1, posa);
        proc(rl1.y, rp1.y, m1.y, 0, posr);  proc(al1.y, ap1.y, m1.y, 1, posa);
        proc(rl1.z, rp1.z, m1.z, 0, posr);  proc(al1.z, ap1.z, m1.z, 1, posa);
        proc(rl1.w, rp1.w, m1.w, 0, posr);  proc(al1.w, ap1.w, m1.w, 1, posa);
    }
    __syncthreads();

    // Merge slot pairs -> logical bins, flush nonzero bins into per-image-op
    // global histograms (u64 atomics). Integer adds: bit-exact vs R=1.
    const size_t j0 = (size_t)img * 2;
    for (int i = tid; i < NBINS; i += T1) {
        unsigned long long v0 = s_hist[0][2 * i] + s_hist[0][2 * i + 1];
        if (v0) atomicAdd(&g_hist[j0 * NBINS + i], v0);
        unsigned long long v1 = s_hist[1][2 * i] + s_hist[1][2 * i + 1];
        if (v1) atomicAdd(&g_hist[(j0 + 1) * NBINS + i], v1);
    }

    // Block-reduce positive-loss sums.
    for (int off = 32; off > 0; off >>= 1) {
        posr += __shfl_down(posr, off);
        posa += __shfl_down(posa, off);
    }
    const int wave = tid >> 6, lane = tid & 63;
    if (lane == 0) { s_red[0][wave] = posr; s_red[1][wave] = posa; }
    __syncthreads();
    if (tid == 0) {
        float pr = 0.f, pa = 0.f;
        for (int w = 0; w < T1 / 64; ++w) { pr += s_red[0][w]; pa += s_red[1][w]; }
        atomicAdd(&g_pos[j0], pr);
        atomicAdd(&g_pos[j0 + 1], pa);
    }
}

// ---------------------------------------------------------------------------
// Kernel 2: per image-op finalize. Decode packed histogram, top-down scan to
// the top-k crossing, proportional split in the boundary bin. Reproduces the
// reference branch structure exactly.
// ---------------------------------------------------------------------------
__global__ __launch_bounds__(256) void maploss_finalize(
    const unsigned long long* __restrict__ g_hist,
    const float* __restrict__ g_pos, const int* __restrict__ neg_rto_p,
    float* __restrict__ out, int batch)
{
    const int j   = blockIdx.x;
    const int tid = threadIdx.x;
    __shared__ unsigned int s_cc[256];
    __shared__ double       s_cs[256];

    const unsigned long long* h = g_hist + (size_t)j * NBINS;
    const int cpb = NBINS / 256;   // 4 bins per thread

    unsigned int c = 0; double s = 0.0;
    #pragma unroll
    for (int i = 0; i < cpb; ++i) {
        unsigned long long v = h[tid * cpb + i];
        c += (unsigned int)(v >> CNT_SHIFT);
        s += (double)(v & SUM_MASK) * INV_FIX;
    }
    s_cc[tid] = c; s_cs[tid] = s;
    __syncthreads();

    if (tid == 0) {
        long long n = 0; double sum_neg = 0.0;
        for (int t = 0; t < 256; ++t) { n += s_cc[t]; sum_neg += s_cs[t]; }
        const long long p = (long long)HW - n;

        const float neg_rto = (float)(*neg_rto_p);
        const double pos_loss = (p > 0) ? (double)g_pos[j] / (double)p : 0.0;
        const float  p_eff    = (p > 0) ? (float)p : FALLBACK_POS;
        const float  k_f      = neg_rto * p_eff;
        const long long k     = (long long)floorf(k_f);

        double topk = 0.0;
        if (k > 0) {
            if (n <= k) {
                topk = sum_neg;   // zeros pad the top-k beyond n
            } else {
                long long cum = 0; double sacc = 0.0; int chunk = 0;
                for (int t = 255; t >= 0; --t) {
                    if (cum + (long long)s_cc[t] >= k) { chunk = t; break; }
                    cum += s_cc[t]; sacc += s_cs[t];
                }
                topk = sacc;
                for (int b = chunk * cpb + cpb - 1; b >= chunk * cpb; --b) {
                    unsigned long long v = h[b];
                    const long long cb = (long long)(v >> CNT_SHIFT);
                    const double    sb = (double)(v & SUM_MASK) * INV_FIX;
                    if (cum + cb >= k) {
                        const long long needed = k - cum;   // 1..cb
                        topk += ((double)needed / (double)cb) * sb;
                        break;
                    }
                    cum += cb; topk += sb;
                }
            }
        }

        const bool use_all = (p > 0) && ((float)n < k_f);
        double neg_loss;
        if (use_all) {
            const double nd = (n > 0) ? (double)n : 1.0;
            neg_loss = sum_neg / nd;
        } else {
            neg_loss = topk / (double)k_f;
        }
        const double contrib = (pos_loss + neg_loss) / (double)batch;
        atomicAdd(out, (float)contrib);
    }
}

// ---------------------------------------------------------------------------
extern "C" void kernel_launch(void* const* d_in, const int* in_sizes, int n_in,
                              void* d_out, int out_size, void* d_ws, size_t ws_size,
                              hipStream_t stream) {
    const float* rlab = (const float*)d_in[0];
    const float* alab = (const float*)d_in[1];
    const float* rpre = (const float*)d_in[2];
    const float* apre = (const float*)d_in[3];
    const float* mask = (const float*)d_in[4];
    const int*   nrto = (const int*)d_in[5];

    const int B = in_sizes[0] / HW;            // 64
    const int J = 2 * B;                       // image-ops

    unsigned long long* g_hist = (unsigned long long*)d_ws;
    float* g_pos = (float*)((char*)d_ws + (size_t)J * NBINS * sizeof(unsigned long long));

    const size_t zbytes = (size_t)J * NBINS * sizeof(unsigned long long)
                        + (size_t)J * sizeof(float);
    hipMemsetAsync(d_ws, 0, zbytes, stream);
    hipMemsetAsync(d_out, 0, sizeof(float), stream);

    dim3 grid1(BPI, B);
    maploss_hist<<<grid1, T1, 0, stream>>>(rlab, alab, rpre, apre, mask,
                                           g_hist, g_pos);
    maploss_finalize<<<J, 256, 0, stream>>>(g_hist, g_pos, nrto,
                                            (float*)d_out, B);
}

// Round 2
// 316.612 us; speedup vs baseline: 1.0010x; 1.0010x over previous
//
#include <hip/hip_runtime.h>

#define HW 262144          // 512*512 pixels per image
#define NBINS 1024         // 10-bit histogram (8 exp | 2 mantissa), value>=0
#define RSLOT 2            // lane-parity replication factor
#define NSLOT (NBINS * RSLOT)
#define BPI 32             // blocks per image in kernel 1 (slice = 8192 px)
#define T1 256             // threads per block, kernel 1 (4 waves)
#define POS_THRESH 0.1f
#define FALLBACK_POS 1000.0f
#define FIX_SCALE 16777216.0f     // 2^24 fixed-point scale for loss sums
#define INV_FIX   (1.0 / 16777216.0)
#define CNT_SHIFT 44
#define SUM_MASK  ((1ULL << CNT_SHIFT) - 1)

// ---------------------------------------------------------------------------
// Kernel 1: one streaming pass. Per block: 8192-px slice of one image.
// Packed LDS histogram (count<<44 | fixed-point sum) of negative losses for
// region+affinity -> ONE ds_add_u64 per negative pixel-op.
//
// v3 lesson: __launch_bounds__(512,8) capped VGPRs at 64; allocator used 28
// and serialized the load burst -> pure latency-bound (VALU 14%, BW 18%,
// DS modest, dur pinned at 117us regardless of occupancy/parity changes).
// Fix: 256 threads @ min 4 waves/EU -> 128-VGPR budget, explicit 3-buffer
// rotation prefetching 2 steps ahead (10 float4 in flight during every
// process phase), fully unrolled with NAMED buffers (no scratch).
// LDS 32.9 KB -> exactly 4 blocks/CU; grid 2048 = 2 clean generations.
// ---------------------------------------------------------------------------
struct V5 { float4 rl, al, rp, ap, m; };

__global__ __launch_bounds__(T1, 4) void maploss_hist(
    const float* __restrict__ rlab, const float* __restrict__ alab,
    const float* __restrict__ rpre, const float* __restrict__ apre,
    const float* __restrict__ mask,
    unsigned long long* __restrict__ g_hist,  // [2*B][NBINS] packed
    float* __restrict__ g_pos)                // [2*B]
{
    __shared__ unsigned long long s_hist[2][NSLOT];   // 32 KB
    __shared__ float s_red[2][T1 / 64];

    const int tid   = threadIdx.x;
    const int slice = blockIdx.x;   // 0..BPI-1
    const int img   = blockIdx.y;   // 0..B-1
    const int par   = tid & 1;      // lane-parity replication slot

    for (int i = tid; i < NSLOT; i += T1) {
        s_hist[0][i] = 0ull;
        s_hist[1][i] = 0ull;
    }
    __syncthreads();

    const size_t base = (size_t)img * HW + (size_t)slice * (HW / BPI);
    const float4* rl4 = (const float4*)(rlab + base);
    const float4* al4 = (const float4*)(alab + base);
    const float4* rp4 = (const float4*)(rpre + base);
    const float4* ap4 = (const float4*)(apre + base);
    const float4* m4  = (const float4*)(mask + base);

    float posr = 0.f, posa = 0.f;

    auto proc = [&](float lab, float pre, float mm, int op, float& pacc) {
        float d = pre - lab;
        float l = d * d * mm;
        const bool neg = !(lab > POS_THRESH);
        pacc += neg ? 0.f : l;                       // branchless (cndmask)
        if (neg) {                                   // single predicated block
            unsigned int b = __float_as_uint(l) >> 21;   // monotone for l>=0
            if (b >= NBINS) b = NBINS - 1;               // safety clamp
            unsigned long long pk = (1ULL << CNT_SHIFT) |
                (unsigned long long)(fminf(l, 2.0f) * FIX_SCALE);
            atomicAdd(&s_hist[op][(b << 1) | par], pk);
        }
    };

    auto ld = [&](V5& v, int i) {
        v.rl = rl4[i]; v.al = al4[i]; v.rp = rp4[i]; v.ap = ap4[i]; v.m = m4[i];
    };
    auto pr = [&](const V5& v) {
        proc(v.rl.x, v.rp.x, v.m.x, 0, posr);  proc(v.al.x, v.ap.x, v.m.x, 1, posa);
        proc(v.rl.y, v.rp.y, v.m.y, 0, posr);  proc(v.al.y, v.ap.y, v.m.y, 1, posa);
        proc(v.rl.z, v.rp.z, v.m.z, 0, posr);  proc(v.al.z, v.ap.z, v.m.z, 1, posa);
        proc(v.rl.w, v.rp.w, v.m.w, 0, posr);  proc(v.al.w, v.ap.w, v.m.w, 1, posa);
    };

    // NV = (HW/BPI)/4 = 2048 float4 per slice; per-thread steps = NV/T1 = 8.
    // 3-buffer rotation, prefetch depth 2, fully unrolled, named buffers.
    V5 va, vb, vc;
    ld(va, tid);
    ld(vb, tid + 1 * T1);
    ld(vc, tid + 2 * T1);  pr(va);          // step 0
    ld(va, tid + 3 * T1);  pr(vb);          // step 1
    ld(vb, tid + 4 * T1);  pr(vc);          // step 2
    ld(vc, tid + 5 * T1);  pr(va);          // step 3
    ld(va, tid + 6 * T1);  pr(vb);          // step 4
    ld(vb, tid + 7 * T1);  pr(vc);          // step 5
    pr(va);                                  // step 6
    pr(vb);                                  // step 7
    __syncthreads();

    // Merge slot pairs -> logical bins, flush nonzero bins into per-image-op
    // global histograms (u64 atomics). Integer adds: bit-exact vs R=1.
    const size_t j0 = (size_t)img * 2;
    for (int i = tid; i < NBINS; i += T1) {
        unsigned long long v0 = s_hist[0][2 * i] + s_hist[0][2 * i + 1];
        if (v0) atomicAdd(&g_hist[j0 * NBINS + i], v0);
        unsigned long long v1 = s_hist[1][2 * i] + s_hist[1][2 * i + 1];
        if (v1) atomicAdd(&g_hist[(j0 + 1) * NBINS + i], v1);
    }

    // Block-reduce positive-loss sums.
    for (int off = 32; off > 0; off >>= 1) {
        posr += __shfl_down(posr, off);
        posa += __shfl_down(posa, off);
    }
    const int wave = tid >> 6, lane = tid & 63;
    if (lane == 0) { s_red[0][wave] = posr; s_red[1][wave] = posa; }
    __syncthreads();
    if (tid == 0) {
        float pr2 = 0.f, pa2 = 0.f;
        for (int w = 0; w < T1 / 64; ++w) { pr2 += s_red[0][w]; pa2 += s_red[1][w]; }
        atomicAdd(&g_pos[j0], pr2);
        atomicAdd(&g_pos[j0 + 1], pa2);
    }
}

// ---------------------------------------------------------------------------
// Kernel 2: per image-op finalize. Decode packed histogram, top-down scan to
// the top-k crossing, proportional split in the boundary bin. Reproduces the
// reference branch structure exactly.
// ---------------------------------------------------------------------------
__global__ __launch_bounds__(256) void maploss_finalize(
    const unsigned long long* __restrict__ g_hist,
    const float* __restrict__ g_pos, const int* __restrict__ neg_rto_p,
    float* __restrict__ out, int batch)
{
    const int j   = blockIdx.x;
    const int tid = threadIdx.x;
    __shared__ unsigned int s_cc[256];
    __shared__ double       s_cs[256];

    const unsigned long long* h = g_hist + (size_t)j * NBINS;
    const int cpb = NBINS / 256;   // 4 bins per thread

    unsigned int c = 0; double s = 0.0;
    #pragma unroll
    for (int i = 0; i < cpb; ++i) {
        unsigned long long v = h[tid * cpb + i];
        c += (unsigned int)(v >> CNT_SHIFT);
        s += (double)(v & SUM_MASK) * INV_FIX;
    }
    s_cc[tid] = c; s_cs[tid] = s;
    __syncthreads();

    if (tid == 0) {
        long long n = 0; double sum_neg = 0.0;
        for (int t = 0; t < 256; ++t) { n += s_cc[t]; sum_neg += s_cs[t]; }
        const long long p = (long long)HW - n;

        const float neg_rto = (float)(*neg_rto_p);
        const double pos_loss = (p > 0) ? (double)g_pos[j] / (double)p : 0.0;
        const float  p_eff    = (p > 0) ? (float)p : FALLBACK_POS;
        const float  k_f      = neg_rto * p_eff;
        const long long k     = (long long)floorf(k_f);

        double topk = 0.0;
        if (k > 0) {
            if (n <= k) {
                topk = sum_neg;   // zeros pad the top-k beyond n
            } else {
                long long cum = 0; double sacc = 0.0; int chunk = 0;
                for (int t = 255; t >= 0; --t) {
                    if (cum + (long long)s_cc[t] >= k) { chunk = t; break; }
                    cum += s_cc[t]; sacc += s_cs[t];
                }
                topk = sacc;
                for (int b = chunk * cpb + cpb - 1; b >= chunk * cpb; --b) {
                    unsigned long long v = h[b];
                    const long long cb = (long long)(v >> CNT_SHIFT);
                    const double    sb = (double)(v & SUM_MASK) * INV_FIX;
                    if (cum + cb >= k) {
                        const long long needed = k - cum;   // 1..cb
                        topk += ((double)needed / (double)cb) * sb;
                        break;
                    }
                    cum += cb; topk += sb;
                }
            }
        }

        const bool use_all = (p > 0) && ((float)n < k_f);
        double neg_loss;
        if (use_all) {
            const double nd = (n > 0) ? (double)n : 1.0;
            neg_loss = sum_neg / nd;
        } else {
            neg_loss = topk / (double)k_f;
        }
        const double contrib = (pos_loss + neg_loss) / (double)batch;
        atomicAdd(out, (float)contrib);
    }
}

// ---------------------------------------------------------------------------
extern "C" void kernel_launch(void* const* d_in, const int* in_sizes, int n_in,
                              void* d_out, int out_size, void* d_ws, size_t ws_size,
                              hipStream_t stream) {
    const float* rlab = (const float*)d_in[0];
    const float* alab = (const float*)d_in[1];
    const float* rpre = (const float*)d_in[2];
    const float* apre = (const float*)d_in[3];
    const float* mask = (const float*)d_in[4];
    const int*   nrto = (const int*)d_in[5];

    const int B = in_sizes[0] / HW;            // 64
    const int J = 2 * B;                       // image-ops

    unsigned long long* g_hist = (unsigned long long*)d_ws;
    float* g_pos = (float*)((char*)d_ws + (size_t)J * NBINS * sizeof(unsigned long long));

    const size_t zbytes = (size_t)J * NBINS * sizeof(unsigned long long)
                        + (size_t)J * sizeof(float);
    hipMemsetAsync(d_ws, 0, zbytes, stream);
    hipMemsetAsync(d_out, 0, sizeof(float), stream);

    dim3 grid1(BPI, B);
    maploss_hist<<<grid1, T1, 0, stream>>>(rlab, alab, rpre, apre, mask,
                                           g_hist, g_pos);
    maploss_finalize<<<J, 256, 0, stream>>>(g_hist, g_pos, nrto,
                                            (float*)d_out, B);
}

// Round 3
// 305.564 us; speedup vs baseline: 1.0372x; 1.0362x over previous
//
#include <hip/hip_runtime.h>

#define HW 262144          // 512*512 pixels per image
#define NBINS 128          // 32 exps x 4 mantissa slots, l in [2^-31, 2)
#define B0BIN 384          // (bits>>21) offset so bin 127 covers l just below 2
#define RSLOT 16           // replicas: slot = bin*16 + (lane&15)
#define NSLOT (NBINS * RSLOT)   // 2048 slots per op-histogram
#define BPI 32             // blocks per image in kernel 1 (slice = 8192 px)
#define T1 256             // threads per block, kernel 1 (4 waves)
#define POS_THRESH 0.1f
#define FALLBACK_POS 1000.0f
#define FIX_SCALE 16777216.0f     // 2^24 fixed-point scale for loss sums
#define INV_FIX   (1.0 / 16777216.0)
#define CNT_SHIFT 44
#define SUM_MASK  ((1ULL << CNT_SHIFT) - 1)

// ---------------------------------------------------------------------------
// Kernel 1: one streaming pass. Per block: 8192-px slice of one image.
// Packed LDS histogram (count<<44 | fixed-point sum) of negative losses.
//
// R2 post-mortem: time pinned at ~114us across 3 structures; arithmetic says
// 2.6 cyc per atomic lane-op with every other pipe idle -> ds_add_u64
// serialization (same-address + same-bank) is the wall. R=2 parity was a
// wash because halving address collisions doubled bank-wrap collisions.
//
// Fix: slot = bin*16 + (lane&15). A u64 slot's bank-pair is slot%16 ==
// lane&15, INDEPENDENT of bin: lanes 0-15 hit 16 distinct bank-pairs
// (zero conflict, zero shared address); only lanes {l,l+16,l+32,l+48}
// share a bank-pair (4-way ~ free per m136) and share an address only on
// equal bins. Bins 1024->128 via exponent clamp (identical 2-mantissa-bit
// resolution over [2^-31,2); sub-2^-31 mass is below fixed-point noise)
// keeps LDS at 32KB -> 4 blocks/CU. Replica merge is integer = bit-exact.
// ---------------------------------------------------------------------------
struct V5 { float4 rl, al, rp, ap, m; };

__global__ __launch_bounds__(T1, 4) void maploss_hist(
    const float* __restrict__ rlab, const float* __restrict__ alab,
    const float* __restrict__ rpre, const float* __restrict__ apre,
    const float* __restrict__ mask,
    unsigned long long* __restrict__ g_hist,  // [2*B][NBINS] packed
    float* __restrict__ g_pos)                // [2*B]
{
    __shared__ unsigned long long s_hist[2][NSLOT];   // 32 KB
    __shared__ float s_red[2][T1 / 64];

    const int tid   = threadIdx.x;
    const int slice = blockIdx.x;   // 0..BPI-1
    const int img   = blockIdx.y;   // 0..B-1
    const int rep   = tid & 15;     // bank-pair-private replica index

    for (int i = tid; i < NSLOT; i += T1) {
        s_hist[0][i] = 0ull;
        s_hist[1][i] = 0ull;
    }
    __syncthreads();

    const size_t base = (size_t)img * HW + (size_t)slice * (HW / BPI);
    const float4* rl4 = (const float4*)(rlab + base);
    const float4* al4 = (const float4*)(alab + base);
    const float4* rp4 = (const float4*)(rpre + base);
    const float4* ap4 = (const float4*)(apre + base);
    const float4* m4  = (const float4*)(mask + base);

    float posr = 0.f, posa = 0.f;

    auto proc = [&](float lab, float pre, float mm, int op, float& pacc) {
        float d = pre - lab;
        float l = d * d * mm;
        const bool neg = !(lab > POS_THRESH);
        pacc += neg ? 0.f : l;                       // branchless (cndmask)
        if (neg) {                                   // single predicated block
            int bi = (int)(__float_as_uint(l) >> 21) - B0BIN;  // monotone, l>=0
            bi = bi < 0 ? 0 : (bi > NBINS - 1 ? NBINS - 1 : bi);
            unsigned long long pk = (1ULL << CNT_SHIFT) |
                (unsigned long long)(fminf(l, 2.0f) * FIX_SCALE);
            atomicAdd(&s_hist[op][(bi << 4) | rep], pk);
        }
    };

    auto ld = [&](V5& v, int i) {
        v.rl = rl4[i]; v.al = al4[i]; v.rp = rp4[i]; v.ap = ap4[i]; v.m = m4[i];
    };
    auto pr = [&](const V5& v) {
        proc(v.rl.x, v.rp.x, v.m.x, 0, posr);  proc(v.al.x, v.ap.x, v.m.x, 1, posa);
        proc(v.rl.y, v.rp.y, v.m.y, 0, posr);  proc(v.al.y, v.ap.y, v.m.y, 1, posa);
        proc(v.rl.z, v.rp.z, v.m.z, 0, posr);  proc(v.al.z, v.ap.z, v.m.z, 1, posa);
        proc(v.rl.w, v.rp.w, v.m.w, 0, posr);  proc(v.al.w, v.ap.w, v.m.w, 1, posa);
    };

    // NV = (HW/BPI)/4 = 2048 float4 per slice; per-thread steps = NV/T1 = 8.
    // 3-buffer rotation, prefetch depth 2, fully unrolled, named buffers.
    V5 va, vb, vc;
    ld(va, tid);
    ld(vb, tid + 1 * T1);
    ld(vc, tid + 2 * T1);  pr(va);          // step 0
    ld(va, tid + 3 * T1);  pr(vb);          // step 1
    ld(vb, tid + 4 * T1);  pr(vc);          // step 2
    ld(vc, tid + 5 * T1);  pr(va);          // step 3
    ld(va, tid + 6 * T1);  pr(vb);          // step 4
    ld(vb, tid + 7 * T1);  pr(vc);          // step 5
    pr(va);                                  // step 6
    pr(vb);                                  // step 7
    __syncthreads();

    // Merge 16 replicas -> logical bins (integer add = bit-exact), flush
    // nonzero bins into per-image-op global histograms (u64 atomics).
    // 256 threads cover exactly 2 ops x 128 bins.
    const size_t j0 = (size_t)img * 2;
    {
        const int op  = tid >> 7;        // 0..1
        const int bin = tid & 127;       // 0..127
        unsigned long long v = 0ull;
        #pragma unroll
        for (int r = 0; r < RSLOT; ++r) v += s_hist[op][(bin << 4) | r];
        if (v) atomicAdd(&g_hist[(j0 + op) * NBINS + bin], v);
    }

    // Block-reduce positive-loss sums.
    for (int off = 32; off > 0; off >>= 1) {
        posr += __shfl_down(posr, off);
        posa += __shfl_down(posa, off);
    }
    const int wave = tid >> 6, lane = tid & 63;
    if (lane == 0) { s_red[0][wave] = posr; s_red[1][wave] = posa; }
    __syncthreads();
    if (tid == 0) {
        float pr2 = 0.f, pa2 = 0.f;
        for (int w = 0; w < T1 / 64; ++w) { pr2 += s_red[0][w]; pa2 += s_red[1][w]; }
        atomicAdd(&g_pos[j0], pr2);
        atomicAdd(&g_pos[j0 + 1], pa2);
    }
}

// ---------------------------------------------------------------------------
// Kernel 2: per image-op finalize. Decode packed 128-bin histogram, top-down
// scan to the top-k crossing, proportional split in the boundary bin.
// Reproduces the reference branch structure exactly.
// ---------------------------------------------------------------------------
__global__ __launch_bounds__(NBINS) void maploss_finalize(
    const unsigned long long* __restrict__ g_hist,
    const float* __restrict__ g_pos, const int* __restrict__ neg_rto_p,
    float* __restrict__ out, int batch)
{
    const int j   = blockIdx.x;
    const int tid = threadIdx.x;
    __shared__ unsigned int s_cc[NBINS];
    __shared__ double       s_cs[NBINS];

    const unsigned long long v = g_hist[(size_t)j * NBINS + tid];
    s_cc[tid] = (unsigned int)(v >> CNT_SHIFT);
    s_cs[tid] = (double)(v & SUM_MASK) * INV_FIX;
    __syncthreads();

    if (tid == 0) {
        long long n = 0; double sum_neg = 0.0;
        for (int t = 0; t < NBINS; ++t) { n += s_cc[t]; sum_neg += s_cs[t]; }
        const long long p = (long long)HW - n;

        const float neg_rto = (float)(*neg_rto_p);
        const double pos_loss = (p > 0) ? (double)g_pos[j] / (double)p : 0.0;
        const float  p_eff    = (p > 0) ? (float)p : FALLBACK_POS;
        const float  k_f      = neg_rto * p_eff;
        const long long k     = (long long)floorf(k_f);

        double topk = 0.0;
        if (k > 0) {
            if (n <= k) {
                topk = sum_neg;   // zeros pad the top-k beyond n
            } else {
                long long cum = 0;
                for (int b = NBINS - 1; b >= 0; --b) {
                    const long long cb = (long long)s_cc[b];
                    const double    sb = s_cs[b];
                    if (cum + cb >= k) {
                        const long long needed = k - cum;   // 1..cb
                        topk += ((double)needed / (double)cb) * sb;
                        break;
                    }
                    cum += cb; topk += sb;
                }
            }
        }

        const bool use_all = (p > 0) && ((float)n < k_f);
        double neg_loss;
        if (use_all) {
            const double nd = (n > 0) ? (double)n : 1.0;
            neg_loss = sum_neg / nd;
        } else {
            neg_loss = topk / (double)k_f;
        }
        const double contrib = (pos_loss + neg_loss) / (double)batch;
        atomicAdd(out, (float)contrib);
    }
}

// ---------------------------------------------------------------------------
extern "C" void kernel_launch(void* const* d_in, const int* in_sizes, int n_in,
                              void* d_out, int out_size, void* d_ws, size_t ws_size,
                              hipStream_t stream) {
    const float* rlab = (const float*)d_in[0];
    const float* alab = (const float*)d_in[1];
    const float* rpre = (const float*)d_in[2];
    const float* apre = (const float*)d_in[3];
    const float* mask = (const float*)d_in[4];
    const int*   nrto = (const int*)d_in[5];

    const int B = in_sizes[0] / HW;            // 64
    const int J = 2 * B;                       // image-ops

    unsigned long long* g_hist = (unsigned long long*)d_ws;
    float* g_pos = (float*)((char*)d_ws + (size_t)J * NBINS * sizeof(unsigned long long));

    const size_t zbytes = (size_t)J * NBINS * sizeof(unsigned long long)
                        + (size_t)J * sizeof(float);
    hipMemsetAsync(d_ws, 0, zbytes, stream);
    hipMemsetAsync(d_out, 0, sizeof(float), stream);

    dim3 grid1(BPI, B);
    maploss_hist<<<grid1, T1, 0, stream>>>(rlab, alab, rpre, apre, mask,
                                           g_hist, g_pos);
    maploss_finalize<<<J, NBINS, 0, stream>>>(g_hist, g_pos, nrto,
                                              (float*)d_out, B);
}